// Round 9
// baseline (319.720 us; speedup 1.0000x reference)
//
#include <hip/hip_runtime.h>
#include <math.h>

#define BB 64
#define SS 512
#define HH 768
#define LL 21
#define STR 513              // eT row stride (odd -> conflict-free columns)
#define INFF __builtin_huge_valf()

__device__ inline float rlf(float v, int i) {
    return __int_as_float(__builtin_amdgcn_readlane(__float_as_int(v), i));
}
__device__ inline float mx3(float a, float b, float c) { return fmaxf(fmaxf(a, b), c); }
__device__ inline float wmax64(float v) {
    #pragma unroll
    for (int off = 32; off; off >>= 1) v = fmaxf(v, __shfl_xor(v, off));
    return v;
}
__device__ inline float rlmax21(float a) {
    float r0 = mx3(rlf(a, 0), rlf(a, 1), rlf(a, 2));
    float r1 = mx3(rlf(a, 3), rlf(a, 4), rlf(a, 5));
    float r2 = mx3(rlf(a, 6), rlf(a, 7), rlf(a, 8));
    float r3 = mx3(rlf(a, 9), rlf(a, 10), rlf(a, 11));
    float r4 = mx3(rlf(a, 12), rlf(a, 13), rlf(a, 14));
    float r5 = mx3(rlf(a, 15), rlf(a, 16), rlf(a, 17));
    float r6 = mx3(rlf(a, 18), rlf(a, 19), rlf(a, 20));
    return mx3(mx3(r0, r1, r2), mx3(r3, r4, r5), r6);
}

// ---------------- K1: emissions = hidden @ W + b ----------------
// 256 blocks x 256 thr; 128 rows/block; K split 2-way (kh). No h-LDS:
// per-row strided float4 reads (line-dense). W chunk double-buffered in LDS.
__global__ __launch_bounds__(256) void k_emis(const float* __restrict__ hidden,
                                              const float* __restrict__ W,
                                              const float* __restrict__ bias,
                                              float* __restrict__ em) {
    __shared__ float Wc[2][2][32][24];   // [buf][kh][k][l]  12288 B
    __shared__ float cmb[128][22];       // 11264 B
    int tid = threadIdx.x;
    int kh = tid >> 7;
    int rloc = tid & 127;
    int r0 = blockIdx.x * 128;
    const float* hrow = hidden + (size_t)(r0 + rloc) * HH + kh * 384;

    float acc[LL];
    #pragma unroll
    for (int l = 0; l < LL; ++l) acc[l] = 0.f;

    float4 rh[8], rn[8];

#define LOADH(R, C) { _Pragma("unroll") for (int p = 0; p < 8; ++p) \
    R[p] = *reinterpret_cast<const float4*>(hrow + (C) * 32 + p * 4); }
#define LOADW(BUF, C) { for (int u = tid; u < 1344; u += 256) { \
    int khu = (u >= 672) ? 1 : 0; int rem = u - khu * 672; \
    int kk = rem / 21, ll2 = rem - kk * 21; \
    Wc[BUF][khu][kk][ll2] = W[(size_t)(khu * 384 + (C) * 32 + kk) * LL + ll2]; } }
#define HVC(R, k) (((k) & 3) == 0 ? R[(k) >> 2].x : (((k) & 3) == 1 ? R[(k) >> 2].y : \
                   (((k) & 3) == 2 ? R[(k) >> 2].z : R[(k) >> 2].w)))
#define COMPUTE(BUF, R) { _Pragma("unroll") for (int k = 0; k < 32; ++k) { \
    float hv = HVC(R, k); \
    const float* wp = &Wc[BUF][kh][k][0]; \
    float4 w0 = *reinterpret_cast<const float4*>(wp); \
    float4 w1 = *reinterpret_cast<const float4*>(wp + 4); \
    float4 w2 = *reinterpret_cast<const float4*>(wp + 8); \
    float4 w3 = *reinterpret_cast<const float4*>(wp + 12); \
    float4 w4 = *reinterpret_cast<const float4*>(wp + 16); \
    float w20 = wp[20]; \
    acc[0]  = fmaf(hv, w0.x, acc[0]);  acc[1]  = fmaf(hv, w0.y, acc[1]); \
    acc[2]  = fmaf(hv, w0.z, acc[2]);  acc[3]  = fmaf(hv, w0.w, acc[3]); \
    acc[4]  = fmaf(hv, w1.x, acc[4]);  acc[5]  = fmaf(hv, w1.y, acc[5]); \
    acc[6]  = fmaf(hv, w1.z, acc[6]);  acc[7]  = fmaf(hv, w1.w, acc[7]); \
    acc[8]  = fmaf(hv, w2.x, acc[8]);  acc[9]  = fmaf(hv, w2.y, acc[9]); \
    acc[10] = fmaf(hv, w2.z, acc[10]); acc[11] = fmaf(hv, w2.w, acc[11]); \
    acc[12] = fmaf(hv, w3.x, acc[12]); acc[13] = fmaf(hv, w3.y, acc[13]); \
    acc[14] = fmaf(hv, w3.z, acc[14]); acc[15] = fmaf(hv, w3.w, acc[15]); \
    acc[16] = fmaf(hv, w4.x, acc[16]); acc[17] = fmaf(hv, w4.y, acc[17]); \
    acc[18] = fmaf(hv, w4.z, acc[18]); acc[19] = fmaf(hv, w4.w, acc[19]); \
    acc[20] = fmaf(hv, w20, acc[20]); } }

    LOADW(0, 0); LOADH(rh, 0);
    __syncthreads();
    for (int c = 0; c < 12; c += 2) {
        LOADW(1, c + 1); LOADH(rn, c + 1);
        COMPUTE(0, rh);
        __syncthreads();
        if (c < 10) { LOADW(0, c + 2); LOADH(rh, c + 2); }
        COMPUTE(1, rn);
        __syncthreads();
    }
#undef LOADH
#undef LOADW
#undef HVC
#undef COMPUTE

    if (kh == 1) {
        #pragma unroll
        for (int l = 0; l < LL; ++l) cmb[rloc][l] = acc[l];
    }
    __syncthreads();
    if (kh == 0) {
        float* emr = em + (size_t)(r0 + rloc) * LL;
        #pragma unroll
        for (int l = 0; l < LL; ++l) emr[l] = acc[l] + cmb[rloc][l] + bias[l];
    }
}

// ---------------- K2: fused scan dispatch (ROLLED loops, batched readlanes) --
// blocks 0-63: Viterbi fwd (S -> Sout [b][j][t]); 64-127: LSE fwd; 128-191: numerator.
__global__ __launch_bounds__(64) void k_scan(const float* __restrict__ em,
                                             const int* __restrict__ attn,
                                             const int* __restrict__ labels,
                                             const float* __restrict__ startT,
                                             const float* __restrict__ endT,
                                             const float* __restrict__ trans,
                                             float* __restrict__ num,
                                             float* __restrict__ denom,
                                             float* __restrict__ Sout) {
    __shared__ float eLT[LL * STR + 8];
    int lane = threadIdx.x;
    int bid = blockIdx.x;
    bool act = lane < LL;
    int jj = act ? lane : (LL - 1);

    if (bid < 128) {
        int b = bid & 63;
        const float* emb = em + (size_t)b * SS * LL;
        const int* mrow = attn + b * SS;

        for (int f = lane; f < (SS * LL) / 4; f += 64) {
            float4 v = *reinterpret_cast<const float4*>(emb + 4 * f);
            unsigned e0 = 4u * (unsigned)f;
            { unsigned t = e0 / 21u,       j = e0 - 21u * t;       eLT[j * STR + t] = v.x; }
            { unsigned e = e0 + 1, t = e / 21u, j = e - 21u * t;   eLT[j * STR + t] = v.y; }
            { unsigned e = e0 + 2, t = e / 21u, j = e - 21u * t;   eLT[j * STR + t] = v.z; }
            { unsigned e = e0 + 3, t = e / 21u, j = e - 21u * t;   eLT[j * STR + t] = v.w; }
        }
        __syncthreads();

        int jbase = jj * STR;
        float A0, A1, A2, A3, B0, B1, B2, B3;

#define LDG(P, G) do { int t4_ = (G) * 4; \
    P##0 = eLT[jbase + t4_];     P##1 = eLT[jbase + t4_ + 1]; \
    P##2 = eLT[jbase + t4_ + 2]; P##3 = eLT[jbase + t4_ + 3]; } while (0)

        if (bid < 64) {
            // ---------------- Viterbi (bit-exact vs R6/R7) ----------------
            float Tc[LL];
            #pragma unroll
            for (int i = 0; i < LL; ++i) Tc[i] = trans[i * LL + jj];
            float* Sgj = Sout + (size_t)b * (LL * SS) + jj * SS;

#define VCORE(EMIT, BIT) do { \
    float sv_[LL]; \
    _Pragma("unroll") for (int i_ = 0; i_ < LL; ++i_) sv_[i_] = rlf(a, i_); \
    __builtin_amdgcn_sched_barrier(0); \
    float cd_[LL]; \
    _Pragma("unroll") for (int i_ = 0; i_ < LL; ++i_) cd_[i_] = sv_[i_] + Tc[i_]; \
    float x0 = mx3(cd_[0], cd_[1], cd_[2]),   x1 = mx3(cd_[3], cd_[4], cd_[5]); \
    float x2 = mx3(cd_[6], cd_[7], cd_[8]),   x3 = mx3(cd_[9], cd_[10], cd_[11]); \
    float x4 = mx3(cd_[12], cd_[13], cd_[14]), x5 = mx3(cd_[15], cd_[16], cd_[17]); \
    float x6 = mx3(cd_[18], cd_[19], cd_[20]); \
    float best = mx3(mx3(x0, x1, x2), mx3(x3, x4, x5), x6); \
    bool mt_ = ((mm >> (BIT)) & 1ull) != 0ull; \
    float an_ = best + (EMIT); \
    a = (mt_ && act) ? an_ : a; \
} while (0)
#define VGROUPR(P, TB, BB0) do { \
    float o0_, o1_, o2_, o3_; \
    VCORE(P##0, (BB0));     o0_ = a; \
    VCORE(P##1, (BB0) + 1); o1_ = a; \
    VCORE(P##2, (BB0) + 2); o2_ = a; \
    VCORE(P##3, (BB0) + 3); o3_ = a; \
    if (act) *reinterpret_cast<float4*>(Sgj + (TB)) = make_float4(o0_, o1_, o2_, o3_); \
} while (0)

            LDG(A, 0); LDG(B, 1);
            int mk0 = mrow[lane];
            unsigned long long mm = __ballot(mk0 != 0);
            mk0 = mrow[64 + lane];
            float a = act ? (startT[lane] + A0) : -INFF;
            // peel gg = 0 (steps 1..7)
            {
                float o0_ = a, o1_, o2_, o3_;
                VCORE(A1, 1); o1_ = a;
                VCORE(A2, 2); o2_ = a;
                VCORE(A3, 3); o3_ = a;
                if (act) *reinterpret_cast<float4*>(Sgj) = make_float4(o0_, o1_, o2_, o3_);
                LDG(A, 2);
                VGROUPR(B, 4, 4);
                LDG(B, 3);
            }
            for (int gg = 1; gg < 64; ++gg) {
                if ((gg & 7) == 0) {
                    mm = __ballot(mk0 != 0);
                    if (gg != 56) mk0 = mrow[((gg >> 3) + 1) * 64 + lane];
                }
                int bb = (gg & 7) * 8;
                VGROUPR(A, 8 * gg, bb);
                LDG(A, 2 * gg + 2);
                VGROUPR(B, 8 * gg + 4, bb + 4);
                LDG(B, 2 * gg + 3);
            }
#undef VCORE
#undef VGROUPR
        } else {
            // ---------------- LSE forward (exp-trick, batched readlanes) ----
            float Ec[LL];
            #pragma unroll
            for (int i = 0; i < LL; ++i) Ec[i] = __expf(trans[i * LL + jj]);

#define LCORE(EMIT, BIT) do { \
    float x_ = __expf(a - M); \
    float sv_[LL]; \
    _Pragma("unroll") for (int i_ = 0; i_ < LL; ++i_) sv_[i_] = rlf(x_, i_); \
    __builtin_amdgcn_sched_barrier(0); \
    float g0_ = sv_[0] * Ec[0]; \
    _Pragma("unroll") for (int i_ = 1; i_ < 7; ++i_)  g0_ = fmaf(sv_[i_], Ec[i_], g0_); \
    float g1_ = sv_[7] * Ec[7]; \
    _Pragma("unroll") for (int i_ = 8; i_ < 14; ++i_) g1_ = fmaf(sv_[i_], Ec[i_], g1_); \
    float g2_ = sv_[14] * Ec[14]; \
    _Pragma("unroll") for (int i_ = 15; i_ < 21; ++i_) g2_ = fmaf(sv_[i_], Ec[i_], g2_); \
    float Ss_ = (g0_ + g1_) + g2_; \
    bool mt_ = ((mm >> (BIT)) & 1ull) != 0ull; \
    float an_ = M + __logf(Ss_) + (EMIT); \
    a = (mt_ && act) ? an_ : a; \
} while (0)

            LDG(A, 0); LDG(B, 1);
            int mk0 = mrow[lane];
            unsigned long long mm = __ballot(mk0 != 0);
            mk0 = mrow[64 + lane];
            float a = act ? (startT[lane] + A0) : -INFF;
            float M = rlmax21(a);
            // peel gg = 0 (steps 1..7)
            {
                LCORE(A1, 1); LCORE(A2, 2); LCORE(A3, 3);
                LDG(A, 2);
                LCORE(B0, 4); LCORE(B1, 5); LCORE(B2, 6); LCORE(B3, 7);
                LDG(B, 3);
            }
            for (int gg = 1; gg < 64; ++gg) {
                if ((gg & 7) == 0) {
                    mm = __ballot(mk0 != 0);
                    if (gg != 56) mk0 = mrow[((gg >> 3) + 1) * 64 + lane];
                }
                M = rlmax21(a);
                int bb = (gg & 7) * 8;
                LCORE(A0, bb);     LCORE(A1, bb + 1); LCORE(A2, bb + 2); LCORE(A3, bb + 3);
                LDG(A, 2 * gg + 2);
                LCORE(B0, bb + 4); LCORE(B1, bb + 5); LCORE(B2, bb + 6); LCORE(B3, bb + 7);
                LDG(B, 2 * gg + 3);
            }
#undef LCORE
            float f = act ? (a + endT[lane]) : -INFF;
            float m = wmax64(f);
            float p = act ? __expf(f - m) : 0.f;
            #pragma unroll
            for (int off = 32; off; off >>= 1) p += __shfl_xor(p, off);
            if (lane == 0) denom[b] = m + __logf(p);
        }
#undef LDG
    } else {
        // ---------------- numerator ----------------
        int b = bid - 128;
        const int* lrow = labels + b * SS;
        const int* arow = attn + b * SS;
        float psum = 0.f;
        int pcnt = 0;
        for (int s = 0; s < 8; ++s) {
            int t = s * 64 + lane;
            int lab = lrow[t];
            int mk = arow[t];
            int valid = (t == 0) ? 1 : ((mk != 0 && lab >= 0) ? 1 : 0);
            if (t >= 1 && valid) {
                int tag = (lab < 0) ? 0 : lab;
                int labp = lrow[t - 1];
                int tagp = (t == 1) ? 0 : ((labp < 0) ? 0 : labp);
                psum += trans[tagp * LL + tag] + em[((size_t)b * SS + t) * LL + tag];
            }
            pcnt += valid;
        }
        #pragma unroll
        for (int off = 32; off; off >>= 1) {
            psum += __shfl_xor(psum, off);
            pcnt += __shfl_xor(pcnt, off);
        }
        int ts = pcnt - 1;
        int labL = lrow[ts];
        int tagL = (ts == 0) ? 0 : ((labL < 0) ? 0 : labL);
        if (lane == 0)
            num[b] = startT[0] + em[(size_t)b * SS * LL + 0] + psum + endT[tagL];
    }
}

// ---------------- K3: backtrack (S staged to LDS; pred recompute + compose) --
__global__ __launch_bounds__(256) void k_back(const float* __restrict__ S,
                                              const int* __restrict__ attn,
                                              const float* __restrict__ endT,
                                              const float* __restrict__ trans,
                                              int* __restrict__ tagsOut) {
    __shared__ float Sl[LL][517];             // 43428 B
    __shared__ unsigned char pred[SS * 24];   // 12288 B
    __shared__ unsigned char mapL[64 * 32];   // 2048 B
    __shared__ float Tl[441];                 // 1764 B
    int tid = threadIdx.x, b = blockIdx.x;
    const float* SB = S + (size_t)b * (LL * SS);
    for (int i = tid; i < 441; i += 256) Tl[i] = trans[i];
    for (int f = tid; f < (LL * SS) / 4; f += 256) {
        float4 v = *reinterpret_cast<const float4*>(SB + 4 * f);
        int j = f >> 7, t0 = (f & 127) * 4;
        Sl[j][t0] = v.x; Sl[j][t0 + 1] = v.y; Sl[j][t0 + 2] = v.z; Sl[j][t0 + 3] = v.w;
    }
    __syncthreads();

    for (int u = tid; u < 511 * LL; u += 256) {
        int t = 1 + u / LL;
        int j = u - (u / LL) * LL;
        unsigned int pj = (unsigned int)j;
        if (attn[b * SS + t] != 0) {
            float bv = Sl[0][t - 1] + Tl[j];
            unsigned int bi = 0;
            #pragma unroll
            for (int i = 1; i < LL; ++i) {
                float c = Sl[i][t - 1] + Tl[i * LL + j];
                bool g = c > bv;            // strict > : first max wins
                bv = g ? c : bv;
                bi = g ? (unsigned int)i : bi;
            }
            pj = bi;
        }
        pred[t * 24 + j] = (unsigned char)pj;
    }
    __syncthreads();

    if (tid < 64) {
        int lane = tid;
        float f = (lane < LL) ? (Sl[lane][SS - 1] + endT[lane]) : -INFF;
        float m = wmax64(f);
        unsigned long long msk = __ballot(f == m);
        int best_last = __ffsll(msk) - 1;

        int tlo = 8 * lane + 1;
        int thi = 8 * lane + 8; if (thi > 511) thi = 511;
        unsigned int BM[LL];
        #pragma unroll
        for (int s = 0; s < LL; ++s) BM[s] = s;
        for (int k = 0; k < 8; ++k) {
            int t = thi - k;
            if (t >= tlo) {
                #pragma unroll
                for (int s = 0; s < LL; ++s) BM[s] = pred[t * 24 + BM[s]];
            }
        }
        #pragma unroll
        for (int s = 0; s < LL; ++s) mapL[lane * 32 + s] = (unsigned char)BM[s];

        #pragma unroll
        for (int kk = 1; kk < 64; kk <<= 1) {
            int p = lane + kk;
            bool vld = p < 64;
            int pp = vld ? p : 0;
            unsigned int P[LL];
            #pragma unroll
            for (int s = 0; s < LL; ++s) {
                unsigned int v = mapL[pp * 32 + s];
                P[s] = vld ? v : (unsigned int)s;
            }
            unsigned int N[LL];
            #pragma unroll
            for (int s = 0; s < LL; ++s) N[s] = mapL[lane * 32 + P[s]];
            #pragma unroll
            for (int s = 0; s < LL; ++s) mapL[lane * 32 + s] = (unsigned char)N[s];
        }

        int st8 = mapL[lane * 32 + best_last];
        int nxt = __shfl(st8, lane + 1);
        int cur = (lane == 63) ? best_last : nxt;
        for (int k = 0; k < 8; ++k) {
            int t = thi - k;
            if (t >= tlo) {
                tagsOut[b * SS + t] = cur;
                cur = pred[t * 24 + cur];
            }
        }
        if (lane == 0) tagsOut[b * SS] = cur;
    }
}

// ---------------- K4: loss + one-hot logits ----------------
__global__ __launch_bounds__(256) void k_out(const float* __restrict__ num,
                                             const float* __restrict__ denom,
                                             const int* __restrict__ tagsW,
                                             const int* __restrict__ attn,
                                             float* __restrict__ out) {
    int gid = blockIdx.x * 256 + threadIdx.x;
    if ((int)blockIdx.x == (int)gridDim.x - 1 && threadIdx.x < 64) {
        float llh = num[threadIdx.x] - denom[threadIdx.x];
        #pragma unroll
        for (int off = 32; off; off >>= 1) llh += __shfl_xor(llh, off);
        if (threadIdx.x == 0) out[0] = -llh / (float)BB;
    }
    if (gid < BB * SS * LL) {
        int bt = gid / LL, l = gid % LL;
        int tag = tagsW[bt];
        int mk  = attn[bt];
        out[1 + gid] = (mk && tag == l) ? 1.f : 0.f;
    }
}

extern "C" void kernel_launch(void* const* d_in, const int* in_sizes, int n_in,
                              void* d_out, int out_size, void* d_ws, size_t ws_size,
                              hipStream_t stream) {
    const float* hidden = (const float*)d_in[0];
    const int*   attn   = (const int*)d_in[1];
    const int*   labels = (const int*)d_in[2];
    const float* W      = (const float*)d_in[3];
    const float* bias   = (const float*)d_in[4];
    const float* startT = (const float*)d_in[5];
    const float* endT   = (const float*)d_in[6];
    const float* trans  = (const float*)d_in[7];
    float* out = (float*)d_out;

    float* wsf   = (float*)d_ws;
    float* em    = wsf;                       // BB*SS*LL
    float* num   = wsf + (size_t)BB * SS * LL;
    float* denom = num + 64;
    int*   tags  = (int*)(denom + 64);        // BB*SS ints
    float* Sbuf  = out + 4;                   // 16B-aligned; overwritten by k_out

    hipLaunchKernelGGL(k_emis, dim3(256), dim3(256), 0, stream, hidden, W, bias, em);
    hipLaunchKernelGGL(k_scan, dim3(192), dim3(64),  0, stream, em, attn, labels,
                       startT, endT, trans, num, denom, Sbuf);
    hipLaunchKernelGGL(k_back, dim3(64),  dim3(256), 0, stream, Sbuf, attn, endT, trans, tags);
    int oh_blocks = (BB * SS * LL + 255) / 256;   // 2688 exactly
    hipLaunchKernelGGL(k_out,  dim3(oh_blocks + 1), dim3(256), 0, stream,
                       num, denom, tags, attn, out);
}

// Round 10
// 219.622 us; speedup vs baseline: 1.4558x; 1.4558x over previous
//
#include <hip/hip_runtime.h>
#include <math.h>

#define BB 64
#define SS 512
#define HH 768
#define LL 21
#define STR 513              // eT row stride (odd -> conflict-free columns)
#define INFF __builtin_huge_valf()

__device__ inline float rlf(float v, int i) {
    return __int_as_float(__builtin_amdgcn_readlane(__float_as_int(v), i));
}
__device__ inline float mx3(float a, float b, float c) { return fmaxf(fmaxf(a, b), c); }
__device__ inline float wmax64(float v) {
    #pragma unroll
    for (int off = 32; off; off >>= 1) v = fmaxf(v, __shfl_xor(v, off));
    return v;
}
__device__ inline float rlmax21(float a) {
    float r0 = mx3(rlf(a, 0), rlf(a, 1), rlf(a, 2));
    float r1 = mx3(rlf(a, 3), rlf(a, 4), rlf(a, 5));
    float r2 = mx3(rlf(a, 6), rlf(a, 7), rlf(a, 8));
    float r3 = mx3(rlf(a, 9), rlf(a, 10), rlf(a, 11));
    float r4 = mx3(rlf(a, 12), rlf(a, 13), rlf(a, 14));
    float r5 = mx3(rlf(a, 15), rlf(a, 16), rlf(a, 17));
    float r6 = mx3(rlf(a, 18), rlf(a, 19), rlf(a, 20));
    return mx3(mx3(r0, r1, r2), mx3(r3, r4, r5), r6);
}

// ---------------- K1: emissions = hidden @ W + b (v5) ----------------
// 512 blocks x 64 thr (1 wave/block, 2 blocks/CU). Row-per-thread: h streamed
// as 2xfloat4/chunk with distance-1 reg prefetch. W 8k-chunk staged through a
// 1.5KB double-buffered LDS buffer, read back as uniform broadcast b128.
// Low VGPR (~64), no spill, no cross-wave barriers.
__global__ __launch_bounds__(64) void k_emis(const float* __restrict__ hidden,
                                             const float* __restrict__ W,
                                             const float* __restrict__ bias,
                                             float* __restrict__ em) {
    __shared__ float Wl[2][8][24];       // 1536 B, rows 16B-aligned
    int lane = threadIdx.x;
    int r = blockIdx.x * 64 + lane;
    const float* hp = hidden + (size_t)r * HH;

    float acc[LL];
    #pragma unroll
    for (int l = 0; l < LL; ++l) acc[l] = 0.f;

    // lane -> 3 staging elements of the 168-float W chunk
    int u0 = lane;               // < 64
    int u1 = lane + 64;          // < 128
    int u2 = lane + 128;         // < 168 for lane < 40
    int k0 = u0 / LL, l0 = u0 - k0 * LL;
    int k1 = u1 / LL, l1 = u1 - k1 * LL;
    int k2 = u2 / LL, l2 = u2 - k2 * LL;
    bool has2 = (u2 < 168);

#define STAGE_ISSUE(C) \
    float w0_ = W[(size_t)(C) * 168 + u0]; \
    float w1_ = W[(size_t)(C) * 168 + u1]; \
    float w2_ = has2 ? W[(size_t)(C) * 168 + u2] : 0.f;
#define STAGE_WRITE(BUF) do { \
    Wl[BUF][k0][l0] = w0_; Wl[BUF][k1][l1] = w1_; \
    if (has2) Wl[BUF][k2][l2] = w2_; } while (0)
#define HVC(k) (((k) & 3) == 0 ? ((k) < 4 ? ha.x : hb.x) : \
                (((k) & 3) == 1 ? ((k) < 4 ? ha.y : hb.y) : \
                (((k) & 3) == 2 ? ((k) < 4 ? ha.z : hb.z) : ((k) < 4 ? ha.w : hb.w))))
#define COMPUTE(BUF) do { \
    _Pragma("unroll") for (int dk = 0; dk < 8; ++dk) { \
        float hv = HVC(dk); \
        const float* wp = &Wl[BUF][dk][0]; \
        float4 q0 = *reinterpret_cast<const float4*>(wp); \
        float4 q1 = *reinterpret_cast<const float4*>(wp + 4); \
        float4 q2 = *reinterpret_cast<const float4*>(wp + 8); \
        float4 q3 = *reinterpret_cast<const float4*>(wp + 12); \
        float4 q4 = *reinterpret_cast<const float4*>(wp + 16); \
        float q20 = wp[20]; \
        acc[0]  = fmaf(hv, q0.x, acc[0]);  acc[1]  = fmaf(hv, q0.y, acc[1]); \
        acc[2]  = fmaf(hv, q0.z, acc[2]);  acc[3]  = fmaf(hv, q0.w, acc[3]); \
        acc[4]  = fmaf(hv, q1.x, acc[4]);  acc[5]  = fmaf(hv, q1.y, acc[5]); \
        acc[6]  = fmaf(hv, q1.z, acc[6]);  acc[7]  = fmaf(hv, q1.w, acc[7]); \
        acc[8]  = fmaf(hv, q2.x, acc[8]);  acc[9]  = fmaf(hv, q2.y, acc[9]); \
        acc[10] = fmaf(hv, q2.z, acc[10]); acc[11] = fmaf(hv, q2.w, acc[11]); \
        acc[12] = fmaf(hv, q3.x, acc[12]); acc[13] = fmaf(hv, q3.y, acc[13]); \
        acc[14] = fmaf(hv, q3.z, acc[14]); acc[15] = fmaf(hv, q3.w, acc[15]); \
        acc[16] = fmaf(hv, q4.x, acc[16]); acc[17] = fmaf(hv, q4.y, acc[17]); \
        acc[18] = fmaf(hv, q4.z, acc[18]); acc[19] = fmaf(hv, q4.w, acc[19]); \
        acc[20] = fmaf(hv, q20, acc[20]); } } while (0)

    // prologue: stage chunk 0, load h chunk 0
    {
        STAGE_ISSUE(0);
        STAGE_WRITE(0);
    }
    float4 ha = *reinterpret_cast<const float4*>(hp);
    float4 hb = *reinterpret_cast<const float4*>(hp + 4);
    __syncthreads();   // single-wave: compiles to waitcnts only

    for (int c = 0; c < 96; ++c) {
        int buf = c & 1;
        float4 na, nb;
        if (c < 95) {
            na = *reinterpret_cast<const float4*>(hp + (c + 1) * 8);
            nb = *reinterpret_cast<const float4*>(hp + (c + 1) * 8 + 4);
            STAGE_ISSUE(c + 1);
            STAGE_WRITE(buf ^ 1);
        }
        COMPUTE(buf);
        ha = na; hb = nb;
        __syncthreads();
    }
#undef STAGE_ISSUE
#undef STAGE_WRITE
#undef HVC
#undef COMPUTE

    float* emr = em + (size_t)r * LL;
    #pragma unroll
    for (int l = 0; l < LL; ++l) emr[l] = acc[l] + bias[l];
}

// ---------------- K2: fused scan dispatch (ROLLED loops, batched readlanes) --
// blocks 0-63: Viterbi fwd (S -> Sout [b][j][t]); 64-127: LSE fwd; 128-191: numerator.
__global__ __launch_bounds__(64) void k_scan(const float* __restrict__ em,
                                             const int* __restrict__ attn,
                                             const int* __restrict__ labels,
                                             const float* __restrict__ startT,
                                             const float* __restrict__ endT,
                                             const float* __restrict__ trans,
                                             float* __restrict__ num,
                                             float* __restrict__ denom,
                                             float* __restrict__ Sout) {
    __shared__ float eLT[LL * STR + 8];
    int lane = threadIdx.x;
    int bid = blockIdx.x;
    bool act = lane < LL;
    int jj = act ? lane : (LL - 1);

    if (bid < 128) {
        int b = bid & 63;
        const float* emb = em + (size_t)b * SS * LL;
        const int* mrow = attn + b * SS;

        for (int f = lane; f < (SS * LL) / 4; f += 64) {
            float4 v = *reinterpret_cast<const float4*>(emb + 4 * f);
            unsigned e0 = 4u * (unsigned)f;
            { unsigned t = e0 / 21u,       j = e0 - 21u * t;       eLT[j * STR + t] = v.x; }
            { unsigned e = e0 + 1, t = e / 21u, j = e - 21u * t;   eLT[j * STR + t] = v.y; }
            { unsigned e = e0 + 2, t = e / 21u, j = e - 21u * t;   eLT[j * STR + t] = v.z; }
            { unsigned e = e0 + 3, t = e / 21u, j = e - 21u * t;   eLT[j * STR + t] = v.w; }
        }
        __syncthreads();

        int jbase = jj * STR;
        float A0, A1, A2, A3, B0, B1, B2, B3;

#define LDG(P, G) do { int t4_ = (G) * 4; \
    P##0 = eLT[jbase + t4_];     P##1 = eLT[jbase + t4_ + 1]; \
    P##2 = eLT[jbase + t4_ + 2]; P##3 = eLT[jbase + t4_ + 3]; } while (0)

        if (bid < 64) {
            // ---------------- Viterbi (bit-exact vs R6-R9) ----------------
            float Tc[LL];
            #pragma unroll
            for (int i = 0; i < LL; ++i) Tc[i] = trans[i * LL + jj];
            float* Sgj = Sout + (size_t)b * (LL * SS) + jj * SS;

#define VCORE(EMIT, BIT) do { \
    float sv_[LL]; \
    _Pragma("unroll") for (int i_ = 0; i_ < LL; ++i_) sv_[i_] = rlf(a, i_); \
    __builtin_amdgcn_sched_barrier(0); \
    float cd_[LL]; \
    _Pragma("unroll") for (int i_ = 0; i_ < LL; ++i_) cd_[i_] = sv_[i_] + Tc[i_]; \
    float x0 = mx3(cd_[0], cd_[1], cd_[2]),   x1 = mx3(cd_[3], cd_[4], cd_[5]); \
    float x2 = mx3(cd_[6], cd_[7], cd_[8]),   x3 = mx3(cd_[9], cd_[10], cd_[11]); \
    float x4 = mx3(cd_[12], cd_[13], cd_[14]), x5 = mx3(cd_[15], cd_[16], cd_[17]); \
    float x6 = mx3(cd_[18], cd_[19], cd_[20]); \
    float best = mx3(mx3(x0, x1, x2), mx3(x3, x4, x5), x6); \
    bool mt_ = ((mm >> (BIT)) & 1ull) != 0ull; \
    float an_ = best + (EMIT); \
    a = (mt_ && act) ? an_ : a; \
} while (0)
#define VGROUPR(P, TB, BB0) do { \
    float o0_, o1_, o2_, o3_; \
    VCORE(P##0, (BB0));     o0_ = a; \
    VCORE(P##1, (BB0) + 1); o1_ = a; \
    VCORE(P##2, (BB0) + 2); o2_ = a; \
    VCORE(P##3, (BB0) + 3); o3_ = a; \
    if (act) *reinterpret_cast<float4*>(Sgj + (TB)) = make_float4(o0_, o1_, o2_, o3_); \
} while (0)

            LDG(A, 0); LDG(B, 1);
            int mk0 = mrow[lane];
            unsigned long long mm = __ballot(mk0 != 0);
            mk0 = mrow[64 + lane];
            float a = act ? (startT[lane] + A0) : -INFF;
            // peel gg = 0 (steps 1..7)
            {
                float o0_ = a, o1_, o2_, o3_;
                VCORE(A1, 1); o1_ = a;
                VCORE(A2, 2); o2_ = a;
                VCORE(A3, 3); o3_ = a;
                if (act) *reinterpret_cast<float4*>(Sgj) = make_float4(o0_, o1_, o2_, o3_);
                LDG(A, 2);
                VGROUPR(B, 4, 4);
                LDG(B, 3);
            }
            for (int gg = 1; gg < 64; ++gg) {
                if ((gg & 7) == 0) {
                    mm = __ballot(mk0 != 0);
                    if (gg != 56) mk0 = mrow[((gg >> 3) + 1) * 64 + lane];
                }
                int bb = (gg & 7) * 8;
                VGROUPR(A, 8 * gg, bb);
                LDG(A, 2 * gg + 2);
                VGROUPR(B, 8 * gg + 4, bb + 4);
                LDG(B, 2 * gg + 3);
            }
#undef VCORE
#undef VGROUPR
        } else {
            // ---------------- LSE forward (exp-trick, batched readlanes) ----
            float Ec[LL];
            #pragma unroll
            for (int i = 0; i < LL; ++i) Ec[i] = __expf(trans[i * LL + jj]);

#define LCORE(EMIT, BIT) do { \
    float x_ = __expf(a - M); \
    float sv_[LL]; \
    _Pragma("unroll") for (int i_ = 0; i_ < LL; ++i_) sv_[i_] = rlf(x_, i_); \
    __builtin_amdgcn_sched_barrier(0); \
    float g0_ = sv_[0] * Ec[0]; \
    _Pragma("unroll") for (int i_ = 1; i_ < 7; ++i_)  g0_ = fmaf(sv_[i_], Ec[i_], g0_); \
    float g1_ = sv_[7] * Ec[7]; \
    _Pragma("unroll") for (int i_ = 8; i_ < 14; ++i_) g1_ = fmaf(sv_[i_], Ec[i_], g1_); \
    float g2_ = sv_[14] * Ec[14]; \
    _Pragma("unroll") for (int i_ = 15; i_ < 21; ++i_) g2_ = fmaf(sv_[i_], Ec[i_], g2_); \
    float Ss_ = (g0_ + g1_) + g2_; \
    bool mt_ = ((mm >> (BIT)) & 1ull) != 0ull; \
    float an_ = M + __logf(Ss_) + (EMIT); \
    a = (mt_ && act) ? an_ : a; \
} while (0)

            LDG(A, 0); LDG(B, 1);
            int mk0 = mrow[lane];
            unsigned long long mm = __ballot(mk0 != 0);
            mk0 = mrow[64 + lane];
            float a = act ? (startT[lane] + A0) : -INFF;
            float M = rlmax21(a);
            // peel gg = 0 (steps 1..7)
            {
                LCORE(A1, 1); LCORE(A2, 2); LCORE(A3, 3);
                LDG(A, 2);
                LCORE(B0, 4); LCORE(B1, 5); LCORE(B2, 6); LCORE(B3, 7);
                LDG(B, 3);
            }
            for (int gg = 1; gg < 64; ++gg) {
                if ((gg & 7) == 0) {
                    mm = __ballot(mk0 != 0);
                    if (gg != 56) mk0 = mrow[((gg >> 3) + 1) * 64 + lane];
                }
                M = rlmax21(a);
                int bb = (gg & 7) * 8;
                LCORE(A0, bb);     LCORE(A1, bb + 1); LCORE(A2, bb + 2); LCORE(A3, bb + 3);
                LDG(A, 2 * gg + 2);
                LCORE(B0, bb + 4); LCORE(B1, bb + 5); LCORE(B2, bb + 6); LCORE(B3, bb + 7);
                LDG(B, 2 * gg + 3);
            }
#undef LCORE
            float f = act ? (a + endT[lane]) : -INFF;
            float m = wmax64(f);
            float p = act ? __expf(f - m) : 0.f;
            #pragma unroll
            for (int off = 32; off; off >>= 1) p += __shfl_xor(p, off);
            if (lane == 0) denom[b] = m + __logf(p);
        }
#undef LDG
    } else {
        // ---------------- numerator ----------------
        int b = bid - 128;
        const int* lrow = labels + b * SS;
        const int* arow = attn + b * SS;
        float psum = 0.f;
        int pcnt = 0;
        for (int s = 0; s < 8; ++s) {
            int t = s * 64 + lane;
            int lab = lrow[t];
            int mk = arow[t];
            int valid = (t == 0) ? 1 : ((mk != 0 && lab >= 0) ? 1 : 0);
            if (t >= 1 && valid) {
                int tag = (lab < 0) ? 0 : lab;
                int labp = lrow[t - 1];
                int tagp = (t == 1) ? 0 : ((labp < 0) ? 0 : labp);
                psum += trans[tagp * LL + tag] + em[((size_t)b * SS + t) * LL + tag];
            }
            pcnt += valid;
        }
        #pragma unroll
        for (int off = 32; off; off >>= 1) {
            psum += __shfl_xor(psum, off);
            pcnt += __shfl_xor(pcnt, off);
        }
        int ts = pcnt - 1;
        int labL = lrow[ts];
        int tagL = (ts == 0) ? 0 : ((labL < 0) ? 0 : labL);
        if (lane == 0)
            num[b] = startT[0] + em[(size_t)b * SS * LL + 0] + psum + endT[tagL];
    }
}

// ---------------- K3: backtrack (S staged to LDS; pred recompute + compose) --
__global__ __launch_bounds__(256) void k_back(const float* __restrict__ S,
                                              const int* __restrict__ attn,
                                              const float* __restrict__ endT,
                                              const float* __restrict__ trans,
                                              int* __restrict__ tagsOut) {
    __shared__ float Sl[LL][517];             // 43428 B
    __shared__ unsigned char pred[SS * 24];   // 12288 B
    __shared__ unsigned char mapL[64 * 32];   // 2048 B
    __shared__ float Tl[441];                 // 1764 B
    int tid = threadIdx.x, b = blockIdx.x;
    const float* SB = S + (size_t)b * (LL * SS);
    for (int i = tid; i < 441; i += 256) Tl[i] = trans[i];
    for (int f = tid; f < (LL * SS) / 4; f += 256) {
        float4 v = *reinterpret_cast<const float4*>(SB + 4 * f);
        int j = f >> 7, t0 = (f & 127) * 4;
        Sl[j][t0] = v.x; Sl[j][t0 + 1] = v.y; Sl[j][t0 + 2] = v.z; Sl[j][t0 + 3] = v.w;
    }
    __syncthreads();

    for (int u = tid; u < 511 * LL; u += 256) {
        int t = 1 + u / LL;
        int j = u - (u / LL) * LL;
        unsigned int pj = (unsigned int)j;
        if (attn[b * SS + t] != 0) {
            float bv = Sl[0][t - 1] + Tl[j];
            unsigned int bi = 0;
            #pragma unroll
            for (int i = 1; i < LL; ++i) {
                float c = Sl[i][t - 1] + Tl[i * LL + j];
                bool g = c > bv;            // strict > : first max wins
                bv = g ? c : bv;
                bi = g ? (unsigned int)i : bi;
            }
            pj = bi;
        }
        pred[t * 24 + j] = (unsigned char)pj;
    }
    __syncthreads();

    if (tid < 64) {
        int lane = tid;
        float f = (lane < LL) ? (Sl[lane][SS - 1] + endT[lane]) : -INFF;
        float m = wmax64(f);
        unsigned long long msk = __ballot(f == m);
        int best_last = __ffsll(msk) - 1;

        int tlo = 8 * lane + 1;
        int thi = 8 * lane + 8; if (thi > 511) thi = 511;
        unsigned int BM[LL];
        #pragma unroll
        for (int s = 0; s < LL; ++s) BM[s] = s;
        for (int k = 0; k < 8; ++k) {
            int t = thi - k;
            if (t >= tlo) {
                #pragma unroll
                for (int s = 0; s < LL; ++s) BM[s] = pred[t * 24 + BM[s]];
            }
        }
        #pragma unroll
        for (int s = 0; s < LL; ++s) mapL[lane * 32 + s] = (unsigned char)BM[s];

        #pragma unroll
        for (int kk = 1; kk < 64; kk <<= 1) {
            int p = lane + kk;
            bool vld = p < 64;
            int pp = vld ? p : 0;
            unsigned int P[LL];
            #pragma unroll
            for (int s = 0; s < LL; ++s) {
                unsigned int v = mapL[pp * 32 + s];
                P[s] = vld ? v : (unsigned int)s;
            }
            unsigned int N[LL];
            #pragma unroll
            for (int s = 0; s < LL; ++s) N[s] = mapL[lane * 32 + P[s]];
            #pragma unroll
            for (int s = 0; s < LL; ++s) mapL[lane * 32 + s] = (unsigned char)N[s];
        }

        int st8 = mapL[lane * 32 + best_last];
        int nxt = __shfl(st8, lane + 1);
        int cur = (lane == 63) ? best_last : nxt;
        for (int k = 0; k < 8; ++k) {
            int t = thi - k;
            if (t >= tlo) {
                tagsOut[b * SS + t] = cur;
                cur = pred[t * 24 + cur];
            }
        }
        if (lane == 0) tagsOut[b * SS] = cur;
    }
}

// ---------------- K4: loss + one-hot logits ----------------
__global__ __launch_bounds__(256) void k_out(const float* __restrict__ num,
                                             const float* __restrict__ denom,
                                             const int* __restrict__ tagsW,
                                             const int* __restrict__ attn,
                                             float* __restrict__ out) {
    int gid = blockIdx.x * 256 + threadIdx.x;
    if ((int)blockIdx.x == (int)gridDim.x - 1 && threadIdx.x < 64) {
        float llh = num[threadIdx.x] - denom[threadIdx.x];
        #pragma unroll
        for (int off = 32; off; off >>= 1) llh += __shfl_xor(llh, off);
        if (threadIdx.x == 0) out[0] = -llh / (float)BB;
    }
    if (gid < BB * SS * LL) {
        int bt = gid / LL, l = gid % LL;
        int tag = tagsW[bt];
        int mk  = attn[bt];
        out[1 + gid] = (mk && tag == l) ? 1.f : 0.f;
    }
}

extern "C" void kernel_launch(void* const* d_in, const int* in_sizes, int n_in,
                              void* d_out, int out_size, void* d_ws, size_t ws_size,
                              hipStream_t stream) {
    const float* hidden = (const float*)d_in[0];
    const int*   attn   = (const int*)d_in[1];
    const int*   labels = (const int*)d_in[2];
    const float* W      = (const float*)d_in[3];
    const float* bias   = (const float*)d_in[4];
    const float* startT = (const float*)d_in[5];
    const float* endT   = (const float*)d_in[6];
    const float* trans  = (const float*)d_in[7];
    float* out = (float*)d_out;

    float* wsf   = (float*)d_ws;
    float* em    = wsf;                       // BB*SS*LL
    float* num   = wsf + (size_t)BB * SS * LL;
    float* denom = num + 64;
    int*   tags  = (int*)(denom + 64);        // BB*SS ints
    float* Sbuf  = out + 4;                   // 16B-aligned; overwritten by k_out

    hipLaunchKernelGGL(k_emis, dim3(512), dim3(64),  0, stream, hidden, W, bias, em);
    hipLaunchKernelGGL(k_scan, dim3(192), dim3(64),  0, stream, em, attn, labels,
                       startT, endT, trans, num, denom, Sbuf);
    hipLaunchKernelGGL(k_back, dim3(64),  dim3(256), 0, stream, Sbuf, attn, endT, trans, tags);
    int oh_blocks = (BB * SS * LL + 255) / 256;   // 2688 exactly
    hipLaunchKernelGGL(k_out,  dim3(oh_blocks + 1), dim3(256), 0, stream,
                       num, denom, tags, attn, out);
}

// Round 14
// 192.007 us; speedup vs baseline: 1.6651x; 1.1438x over previous
//
#include <hip/hip_runtime.h>
#include <math.h>

#define BB 64
#define SS 512
#define HH 768
#define LL 21
#define STR 513              // eT row stride (odd -> conflict-free columns)
#define INFF __builtin_huge_valf()

__device__ inline float rlf(float v, int i) {
    return __int_as_float(__builtin_amdgcn_readlane(__float_as_int(v), i));
}
__device__ inline float mx3(float a, float b, float c) { return fmaxf(fmaxf(a, b), c); }
__device__ inline float wmax64(float v) {
    #pragma unroll
    for (int off = 32; off; off >>= 1) v = fmaxf(v, __shfl_xor(v, off));
    return v;
}
__device__ inline float rlmax21(float a) {
    float r0 = mx3(rlf(a, 0), rlf(a, 1), rlf(a, 2));
    float r1 = mx3(rlf(a, 3), rlf(a, 4), rlf(a, 5));
    float r2 = mx3(rlf(a, 6), rlf(a, 7), rlf(a, 8));
    float r3 = mx3(rlf(a, 9), rlf(a, 10), rlf(a, 11));
    float r4 = mx3(rlf(a, 12), rlf(a, 13), rlf(a, 14));
    float r5 = mx3(rlf(a, 15), rlf(a, 16), rlf(a, 17));
    float r6 = mx3(rlf(a, 18), rlf(a, 19), rlf(a, 20));
    return mx3(mx3(r0, r1, r2), mx3(r3, r4, r5), r6);
}

// ---------------- K1: emissions = hidden @ W + b (v6) ----------------
// 512 blocks x 256 thr (8 waves/CU). Block owns 64 rows; each of the 4 waves
// owns a 192-k quarter of those rows (lane = row). W is read through the
// SCALAR pipe (readfirstlane-uniform quarter base -> s_load -> SGPR FMA
// operand): no LDS traffic, no W VGPRs. h: float4[4] A/B register chunks
// (compile-time indices only). One barrier total (final 4-way LDS combine).
#define FMA21(HV, WB) do { \
    _Pragma("unroll") for (int l_ = 0; l_ < LL; ++l_) \
        acc[l_] = fmaf((HV), (WB)[l_], acc[l_]); } while (0)

__global__ __launch_bounds__(256) void k_emis(const float* __restrict__ hidden,
                                              const float* __restrict__ W,
                                              const float* __restrict__ bias,
                                              float* __restrict__ em) {
    __shared__ float part[3][64][22];    // 16.9 KB
    int tid = threadIdx.x;
    int wq = __builtin_amdgcn_readfirstlane(tid >> 6);   // wave-uniform 0..3
    int lane = tid & 63;
    int r = blockIdx.x * 64 + lane;
    const float* hp = hidden + (size_t)r * HH + wq * 192;
    const float* Wq = W + wq * 192 * LL;                 // uniform -> scalar loads

    float acc[LL];
    #pragma unroll
    for (int l = 0; l < LL; ++l) acc[l] = 0.f;

    float4 ha[4], hb[4];

    #pragma unroll
    for (int q = 0; q < 4; ++q)
        ha[q] = reinterpret_cast<const float4*>(hp)[q];

    for (int c = 0; c < 12; c += 2) {
        if (c < 11) {
            #pragma unroll
            for (int q = 0; q < 4; ++q)
                hb[q] = reinterpret_cast<const float4*>(hp + (c + 1) * 16)[q];
        }
        {   // compute chunk c from ha
            const float* wb = Wq + c * 16 * LL;
            #pragma unroll
            for (int q = 0; q < 4; ++q) {
                float4 v = ha[q];
                const float* w0 = wb + (q * 4) * LL;
                FMA21(v.x, w0);
                FMA21(v.y, w0 + LL);
                FMA21(v.z, w0 + 2 * LL);
                FMA21(v.w, w0 + 3 * LL);
            }
        }
        if (c < 10) {
            #pragma unroll
            for (int q = 0; q < 4; ++q)
                ha[q] = reinterpret_cast<const float4*>(hp + (c + 2) * 16)[q];
        }
        {   // compute chunk c+1 from hb
            const float* wb = Wq + (c + 1) * 16 * LL;
            #pragma unroll
            for (int q = 0; q < 4; ++q) {
                float4 v = hb[q];
                const float* w0 = wb + (q * 4) * LL;
                FMA21(v.x, w0);
                FMA21(v.y, w0 + LL);
                FMA21(v.z, w0 + 2 * LL);
                FMA21(v.w, w0 + 3 * LL);
            }
        }
    }

    if (wq > 0) {
        #pragma unroll
        for (int l = 0; l < LL; ++l) part[wq - 1][lane][l] = acc[l];
    }
    __syncthreads();
    if (wq == 0) {
        float* emr = em + (size_t)r * LL;
        #pragma unroll
        for (int l = 0; l < LL; ++l)
            emr[l] = acc[l] + part[0][lane][l] + part[1][lane][l] + part[2][lane][l] + bias[l];
    }
}
#undef FMA21

// ---------------- K2: fused scan dispatch (ROLLED loops, batched readlanes) --
// blocks 0-63: Viterbi fwd (S -> Sout [b][j][t]); 64-127: LSE fwd; 128-191: numerator.
__global__ __launch_bounds__(64) void k_scan(const float* __restrict__ em,
                                             const int* __restrict__ attn,
                                             const int* __restrict__ labels,
                                             const float* __restrict__ startT,
                                             const float* __restrict__ endT,
                                             const float* __restrict__ trans,
                                             float* __restrict__ num,
                                             float* __restrict__ denom,
                                             float* __restrict__ Sout) {
    __shared__ float eLT[LL * STR + 8];
    int lane = threadIdx.x;
    int bid = blockIdx.x;
    bool act = lane < LL;
    int jj = act ? lane : (LL - 1);

    if (bid < 128) {
        int b = bid & 63;
        const float* emb = em + (size_t)b * SS * LL;
        const int* mrow = attn + b * SS;

        for (int f = lane; f < (SS * LL) / 4; f += 64) {
            float4 v = *reinterpret_cast<const float4*>(emb + 4 * f);
            unsigned e0 = 4u * (unsigned)f;
            { unsigned t = e0 / 21u,       j = e0 - 21u * t;       eLT[j * STR + t] = v.x; }
            { unsigned e = e0 + 1, t = e / 21u, j = e - 21u * t;   eLT[j * STR + t] = v.y; }
            { unsigned e = e0 + 2, t = e / 21u, j = e - 21u * t;   eLT[j * STR + t] = v.z; }
            { unsigned e = e0 + 3, t = e / 21u, j = e - 21u * t;   eLT[j * STR + t] = v.w; }
        }
        __syncthreads();

        int jbase = jj * STR;
        float A0, A1, A2, A3, B0, B1, B2, B3;

#define LDG(P, G) do { int t4_ = (G) * 4; \
    P##0 = eLT[jbase + t4_];     P##1 = eLT[jbase + t4_ + 1]; \
    P##2 = eLT[jbase + t4_ + 2]; P##3 = eLT[jbase + t4_ + 3]; } while (0)

        if (bid < 64) {
            // ---------------- Viterbi (bit-exact vs R6-R10) ----------------
            float Tc[LL];
            #pragma unroll
            for (int i = 0; i < LL; ++i) Tc[i] = trans[i * LL + jj];
            float* Sgj = Sout + (size_t)b * (LL * SS) + jj * SS;

#define VCORE(EMIT, BIT) do { \
    float sv_[LL]; \
    _Pragma("unroll") for (int i_ = 0; i_ < LL; ++i_) sv_[i_] = rlf(a, i_); \
    __builtin_amdgcn_sched_barrier(0); \
    float cd_[LL]; \
    _Pragma("unroll") for (int i_ = 0; i_ < LL; ++i_) cd_[i_] = sv_[i_] + Tc[i_]; \
    float x0 = mx3(cd_[0], cd_[1], cd_[2]),   x1 = mx3(cd_[3], cd_[4], cd_[5]); \
    float x2 = mx3(cd_[6], cd_[7], cd_[8]),   x3 = mx3(cd_[9], cd_[10], cd_[11]); \
    float x4 = mx3(cd_[12], cd_[13], cd_[14]), x5 = mx3(cd_[15], cd_[16], cd_[17]); \
    float x6 = mx3(cd_[18], cd_[19], cd_[20]); \
    float best = mx3(mx3(x0, x1, x2), mx3(x3, x4, x5), x6); \
    bool mt_ = ((mm >> (BIT)) & 1ull) != 0ull; \
    float an_ = best + (EMIT); \
    a = (mt_ && act) ? an_ : a; \
} while (0)
#define VGROUPR(P, TB, BB0) do { \
    float o0_, o1_, o2_, o3_; \
    VCORE(P##0, (BB0));     o0_ = a; \
    VCORE(P##1, (BB0) + 1); o1_ = a; \
    VCORE(P##2, (BB0) + 2); o2_ = a; \
    VCORE(P##3, (BB0) + 3); o3_ = a; \
    if (act) *reinterpret_cast<float4*>(Sgj + (TB)) = make_float4(o0_, o1_, o2_, o3_); \
} while (0)

            LDG(A, 0); LDG(B, 1);
            int mk0 = mrow[lane];
            unsigned long long mm = __ballot(mk0 != 0);
            mk0 = mrow[64 + lane];
            float a = act ? (startT[lane] + A0) : -INFF;
            // peel gg = 0 (steps 1..7)
            {
                float o0_ = a, o1_, o2_, o3_;
                VCORE(A1, 1); o1_ = a;
                VCORE(A2, 2); o2_ = a;
                VCORE(A3, 3); o3_ = a;
                if (act) *reinterpret_cast<float4*>(Sgj) = make_float4(o0_, o1_, o2_, o3_);
                LDG(A, 2);
                VGROUPR(B, 4, 4);
                LDG(B, 3);
            }
            for (int gg = 1; gg < 64; ++gg) {
                if ((gg & 7) == 0) {
                    mm = __ballot(mk0 != 0);
                    if (gg != 56) mk0 = mrow[((gg >> 3) + 1) * 64 + lane];
                }
                int bb = (gg & 7) * 8;
                VGROUPR(A, 8 * gg, bb);
                LDG(A, 2 * gg + 2);
                VGROUPR(B, 8 * gg + 4, bb + 4);
                LDG(B, 2 * gg + 3);
            }
#undef VCORE
#undef VGROUPR
        } else {
            // ---------------- LSE forward (exp-trick, batched readlanes) ----
            float Ec[LL];
            #pragma unroll
            for (int i = 0; i < LL; ++i) Ec[i] = __expf(trans[i * LL + jj]);

#define LCORE(EMIT, BIT) do { \
    float x_ = __expf(a - M); \
    float sv_[LL]; \
    _Pragma("unroll") for (int i_ = 0; i_ < LL; ++i_) sv_[i_] = rlf(x_, i_); \
    __builtin_amdgcn_sched_barrier(0); \
    float g0_ = sv_[0] * Ec[0]; \
    _Pragma("unroll") for (int i_ = 1; i_ < 7; ++i_)  g0_ = fmaf(sv_[i_], Ec[i_], g0_); \
    float g1_ = sv_[7] * Ec[7]; \
    _Pragma("unroll") for (int i_ = 8; i_ < 14; ++i_) g1_ = fmaf(sv_[i_], Ec[i_], g1_); \
    float g2_ = sv_[14] * Ec[14]; \
    _Pragma("unroll") for (int i_ = 15; i_ < 21; ++i_) g2_ = fmaf(sv_[i_], Ec[i_], g2_); \
    float Ss_ = (g0_ + g1_) + g2_; \
    bool mt_ = ((mm >> (BIT)) & 1ull) != 0ull; \
    float an_ = M + __logf(Ss_) + (EMIT); \
    a = (mt_ && act) ? an_ : a; \
} while (0)

            LDG(A, 0); LDG(B, 1);
            int mk0 = mrow[lane];
            unsigned long long mm = __ballot(mk0 != 0);
            mk0 = mrow[64 + lane];
            float a = act ? (startT[lane] + A0) : -INFF;
            float M = rlmax21(a);
            // peel gg = 0 (steps 1..7)
            {
                LCORE(A1, 1); LCORE(A2, 2); LCORE(A3, 3);
                LDG(A, 2);
                LCORE(B0, 4); LCORE(B1, 5); LCORE(B2, 6); LCORE(B3, 7);
                LDG(B, 3);
            }
            for (int gg = 1; gg < 64; ++gg) {
                if ((gg & 7) == 0) {
                    mm = __ballot(mk0 != 0);
                    if (gg != 56) mk0 = mrow[((gg >> 3) + 1) * 64 + lane];
                }
                M = rlmax21(a);
                int bb = (gg & 7) * 8;
                LCORE(A0, bb);     LCORE(A1, bb + 1); LCORE(A2, bb + 2); LCORE(A3, bb + 3);
                LDG(A, 2 * gg + 2);
                LCORE(B0, bb + 4); LCORE(B1, bb + 5); LCORE(B2, bb + 6); LCORE(B3, bb + 7);
                LDG(B, 2 * gg + 3);
            }
#undef LCORE
            float f = act ? (a + endT[lane]) : -INFF;
            float m = wmax64(f);
            float p = act ? __expf(f - m) : 0.f;
            #pragma unroll
            for (int off = 32; off; off >>= 1) p += __shfl_xor(p, off);
            if (lane == 0) denom[b] = m + __logf(p);
        }
#undef LDG
    } else {
        // ---------------- numerator ----------------
        int b = bid - 128;
        const int* lrow = labels + b * SS;
        const int* arow = attn + b * SS;
        float psum = 0.f;
        int pcnt = 0;
        for (int s = 0; s < 8; ++s) {
            int t = s * 64 + lane;
            int lab = lrow[t];
            int mk = arow[t];
            int valid = (t == 0) ? 1 : ((mk != 0 && lab >= 0) ? 1 : 0);
            if (t >= 1 && valid) {
                int tag = (lab < 0) ? 0 : lab;
                int labp = lrow[t - 1];
                int tagp = (t == 1) ? 0 : ((labp < 0) ? 0 : labp);
                psum += trans[tagp * LL + tag] + em[((size_t)b * SS + t) * LL + tag];
            }
            pcnt += valid;
        }
        #pragma unroll
        for (int off = 32; off; off >>= 1) {
            psum += __shfl_xor(psum, off);
            pcnt += __shfl_xor(pcnt, off);
        }
        int ts = pcnt - 1;
        int labL = lrow[ts];
        int tagL = (ts == 0) ? 0 : ((labL < 0) ? 0 : labL);
        if (lane == 0)
            num[b] = startT[0] + em[(size_t)b * SS * LL + 0] + psum + endT[tagL];
    }
}

// ---------------- K3: backtrack (S staged to LDS; pred recompute + compose) --
__global__ __launch_bounds__(256) void k_back(const float* __restrict__ S,
                                              const int* __restrict__ attn,
                                              const float* __restrict__ endT,
                                              const float* __restrict__ trans,
                                              int* __restrict__ tagsOut) {
    __shared__ float Sl[LL][517];             // 43428 B
    __shared__ unsigned char pred[SS * 24];   // 12288 B
    __shared__ unsigned char mapL[64 * 32];   // 2048 B
    __shared__ float Tl[441];                 // 1764 B
    int tid = threadIdx.x, b = blockIdx.x;
    const float* SB = S + (size_t)b * (LL * SS);
    for (int i = tid; i < 441; i += 256) Tl[i] = trans[i];
    for (int f = tid; f < (LL * SS) / 4; f += 256) {
        float4 v = *reinterpret_cast<const float4*>(SB + 4 * f);
        int j = f >> 7, t0 = (f & 127) * 4;
        Sl[j][t0] = v.x; Sl[j][t0 + 1] = v.y; Sl[j][t0 + 2] = v.z; Sl[j][t0 + 3] = v.w;
    }
    __syncthreads();

    for (int u = tid; u < 511 * LL; u += 256) {
        int t = 1 + u / LL;
        int j = u - (u / LL) * LL;
        unsigned int pj = (unsigned int)j;
        if (attn[b * SS + t] != 0) {
            float bv = Sl[0][t - 1] + Tl[j];
            unsigned int bi = 0;
            #pragma unroll
            for (int i = 1; i < LL; ++i) {
                float c = Sl[i][t - 1] + Tl[i * LL + j];
                bool g = c > bv;            // strict > : first max wins
                bv = g ? c : bv;
                bi = g ? (unsigned int)i : bi;
            }
            pj = bi;
        }
        pred[t * 24 + j] = (unsigned char)pj;
    }
    __syncthreads();

    if (tid < 64) {
        int lane = tid;
        float f = (lane < LL) ? (Sl[lane][SS - 1] + endT[lane]) : -INFF;
        float m = wmax64(f);
        unsigned long long msk = __ballot(f == m);
        int best_last = __ffsll(msk) - 1;

        int tlo = 8 * lane + 1;
        int thi = 8 * lane + 8; if (thi > 511) thi = 511;
        unsigned int BM[LL];
        #pragma unroll
        for (int s = 0; s < LL; ++s) BM[s] = s;
        for (int k = 0; k < 8; ++k) {
            int t = thi - k;
            if (t >= tlo) {
                #pragma unroll
                for (int s = 0; s < LL; ++s) BM[s] = pred[t * 24 + BM[s]];
            }
        }
        #pragma unroll
        for (int s = 0; s < LL; ++s) mapL[lane * 32 + s] = (unsigned char)BM[s];

        #pragma unroll
        for (int kk = 1; kk < 64; kk <<= 1) {
            int p = lane + kk;
            bool vld = p < 64;
            int pp = vld ? p : 0;
            unsigned int P[LL];
            #pragma unroll
            for (int s = 0; s < LL; ++s) {
                unsigned int v = mapL[pp * 32 + s];
                P[s] = vld ? v : (unsigned int)s;
            }
            unsigned int N[LL];
            #pragma unroll
            for (int s = 0; s < LL; ++s) N[s] = mapL[lane * 32 + P[s]];
            #pragma unroll
            for (int s = 0; s < LL; ++s) mapL[lane * 32 + s] = (unsigned char)N[s];
        }

        int st8 = mapL[lane * 32 + best_last];
        int nxt = __shfl(st8, lane + 1);
        int cur = (lane == 63) ? best_last : nxt;
        for (int k = 0; k < 8; ++k) {
            int t = thi - k;
            if (t >= tlo) {
                tagsOut[b * SS + t] = cur;
                cur = pred[t * 24 + cur];
            }
        }
        if (lane == 0) tagsOut[b * SS] = cur;
    }
}

// ---------------- K4: loss + one-hot logits ----------------
__global__ __launch_bounds__(256) void k_out(const float* __restrict__ num,
                                             const float* __restrict__ denom,
                                             const int* __restrict__ tagsW,
                                             const int* __restrict__ attn,
                                             float* __restrict__ out) {
    int gid = blockIdx.x * 256 + threadIdx.x;
    if ((int)blockIdx.x == (int)gridDim.x - 1 && threadIdx.x < 64) {
        float llh = num[threadIdx.x] - denom[threadIdx.x];
        #pragma unroll
        for (int off = 32; off; off >>= 1) llh += __shfl_xor(llh, off);
        if (threadIdx.x == 0) out[0] = -llh / (float)BB;
    }
    if (gid < BB * SS * LL) {
        int bt = gid / LL, l = gid % LL;
        int tag = tagsW[bt];
        int mk  = attn[bt];
        out[1 + gid] = (mk && tag == l) ? 1.f : 0.f;
    }
}

extern "C" void kernel_launch(void* const* d_in, const int* in_sizes, int n_in,
                              void* d_out, int out_size, void* d_ws, size_t ws_size,
                              hipStream_t stream) {
    const float* hidden = (const float*)d_in[0];
    const int*   attn   = (const int*)d_in[1];
    const int*   labels = (const int*)d_in[2];
    const float* W      = (const float*)d_in[3];
    const float* bias   = (const float*)d_in[4];
    const float* startT = (const float*)d_in[5];
    const float* endT   = (const float*)d_in[6];
    const float* trans  = (const float*)d_in[7];
    float* out = (float*)d_out;

    float* wsf   = (float*)d_ws;
    float* em    = wsf;                       // BB*SS*LL
    float* num   = wsf + (size_t)BB * SS * LL;
    float* denom = num + 64;
    int*   tags  = (int*)(denom + 64);        // BB*SS ints
    float* Sbuf  = out + 4;                   // 16B-aligned; overwritten by k_out

    hipLaunchKernelGGL(k_emis, dim3(512), dim3(256), 0, stream, hidden, W, bias, em);
    hipLaunchKernelGGL(k_scan, dim3(192), dim3(64),  0, stream, em, attn, labels,
                       startT, endT, trans, num, denom, Sbuf);
    hipLaunchKernelGGL(k_back, dim3(64),  dim3(256), 0, stream, Sbuf, attn, endT, trans, tags);
    int oh_blocks = (BB * SS * LL + 255) / 256;   // 2688 exactly
    hipLaunchKernelGGL(k_out,  dim3(oh_blocks + 1), dim3(256), 0, stream,
                       num, denom, tags, attn, out);
}